// Round 1
// baseline (211.583 us; speedup 1.0000x reference)
//
#include <hip/hip_runtime.h>

constexpr int POOL = 7;
constexpr int NC = 256;   // channels

__global__ __launch_bounds__(256)
void roi_align_kernel(const float* __restrict__ boxes,
                      const int*   __restrict__ ishape,
                      const float* __restrict__ p2,
                      const float* __restrict__ p3,
                      const float* __restrict__ p4,
                      const float* __restrict__ p5,
                      float*       __restrict__ out,
                      int B, int N)
{
    int tid  = blockIdx.x * 256 + threadIdx.x;
    int c4   = tid & 63;          // this lane's float4 channel group (c = 4*c4..4*c4+3)
    int cell = tid >> 6;          // (b,n,i,j)
    if (cell >= B * N * POOL * POOL) return;

    int j = cell % POOL;
    int i = (cell / POOL) % POOL;
    int n = (cell / (POOL * POOL)) % N;
    int b = cell / (POOL * POOL * N);

    const float* bp = boxes + 4 * (b * N + n);
    float y1 = bp[0], x1 = bp[1], y2 = bp[2], x2 = bp[3];

    // ---- level selection (matches jnp: clip(4 + round(log2(sqrt(hw)/(224/sqrt(area)))), 2, 5)) ----
    float area  = (float)(ishape[0] * ishape[1]);
    float denom = 224.0f / sqrtf(area);
    float roi   = log2f(sqrtf((y2 - y1) * (x2 - x1)) / denom);
    int lvl = 4 + (int)rintf(roi);
    lvl = lvl < 2 ? 2 : (lvl > 5 ? 5 : lvl);

    const float* fm; int H;
    if      (lvl == 2) { fm = p2; H = 256; }
    else if (lvl == 3) { fm = p3; H = 128; }
    else if (lvl == 4) { fm = p4; H = 64;  }
    else               { fm = p5; H = 32;  }
    const int W = H;
    const float Hf = (float)H, Wf = (float)W;

    // ---- rounded, ordered box corners at this level ----
    float by1 = rintf(y1 * Hf), bx1 = rintf(x1 * Wf);
    float by2 = rintf(y2 * Hf), bx2 = rintf(x2 * Wf);
    float py1 = fminf(by1, by2), px1 = fminf(bx1, bx2);
    float py2 = fmaxf(by1, by2), px2 = fmaxf(bx1, bx2);

    float* op = out + (size_t)cell * NC + (size_t)c4 * 4;

    if (py1 + px1 + py2 + px2 == 0.0f) {
        float4 z = {0.f, 0.f, 0.f, 0.f};
        *(float4*)op = z;
        return;
    }

    const float A = -0.5f;

    // ---- y-axis taps & cubic weights for this i ----
    int iy[4]; float wy[4];
    {
        float span = py2 - py1;
        float grid = ((float)i + 0.5f) / (float)POOL;
        float s = py1 + grid * span - 0.5f;
        float f = floorf(s);
        float t = s - f;
        float hi_c = fmaxf(py2 - 1.0f, py1);
        float maxi = Hf - 1.0f;
        #pragma unroll
        for (int k = 0; k < 4; ++k) {
            float idx = f + (float)(k - 1);
            idx = fminf(fmaxf(idx, py1), hi_c);   // clip to [lo, max(hi-1, lo)]
            idx = fminf(fmaxf(idx, 0.0f), maxi);  // clip to [0, H-1]
            iy[k] = (int)idx;
        }
        float t2 = t * t, t3 = t2 * t;
        float u = 1.0f - t, u2 = u * u, u3 = u2 * u;
        wy[0] = A * (t3 - 2.0f * t2 + t);
        wy[1] = (A + 2.0f) * t3 - (A + 3.0f) * t2 + 1.0f;
        wy[2] = (A + 2.0f) * u3 - (A + 3.0f) * u2 + 1.0f;
        wy[3] = A * (t2 - t3);
    }

    // ---- x-axis taps & cubic weights for this j ----
    int ix[4]; float wx[4];
    {
        float span = px2 - px1;
        float grid = ((float)j + 0.5f) / (float)POOL;
        float s = px1 + grid * span - 0.5f;
        float f = floorf(s);
        float t = s - f;
        float hi_c = fmaxf(px2 - 1.0f, px1);
        float maxi = Wf - 1.0f;
        #pragma unroll
        for (int l = 0; l < 4; ++l) {
            float idx = f + (float)(l - 1);
            idx = fminf(fmaxf(idx, px1), hi_c);
            idx = fminf(fmaxf(idx, 0.0f), maxi);
            ix[l] = (int)idx;
        }
        float t2 = t * t, t3 = t2 * t;
        float u = 1.0f - t, u2 = u * u, u3 = u2 * u;
        wx[0] = A * (t3 - 2.0f * t2 + t);
        wx[1] = (A + 2.0f) * t3 - (A + 3.0f) * t2 + 1.0f;
        wx[2] = (A + 2.0f) * u3 - (A + 3.0f) * u2 + 1.0f;
        wx[3] = A * (t2 - t3);
    }

    // ---- 4x4 tap gather-accumulate over this lane's 4 channels ----
    float4 acc = {0.f, 0.f, 0.f, 0.f};
    const size_t chan_off = (size_t)c4 * 4;
    const size_t bbase = (size_t)b * H * W * NC + chan_off;
    #pragma unroll
    for (int k = 0; k < 4; ++k) {
        const float* row = fm + bbase + (size_t)iy[k] * (size_t)(W * NC);
        #pragma unroll
        for (int l = 0; l < 4; ++l) {
            float wgt = wy[k] * wx[l];
            float4 v = *(const float4*)(row + (size_t)ix[l] * NC);
            acc.x += wgt * v.x;
            acc.y += wgt * v.y;
            acc.z += wgt * v.z;
            acc.w += wgt * v.w;
        }
    }
    *(float4*)op = acc;
}

extern "C" void kernel_launch(void* const* d_in, const int* in_sizes, int n_in,
                              void* d_out, int out_size, void* d_ws, size_t ws_size,
                              hipStream_t stream) {
    const float* boxes  = (const float*)d_in[0];
    const int*   ishape = (const int*)d_in[1];
    const float* p2     = (const float*)d_in[2];
    const float* p3     = (const float*)d_in[3];
    const float* p4     = (const float*)d_in[4];
    const float* p5     = (const float*)d_in[5];
    float* out = (float*)d_out;

    int B = in_sizes[2] / (256 * 256 * 256);   // p2 = B x 256 x 256 x 256
    int N = in_sizes[0] / (4 * B);             // boxes = B x N x 4

    int total_threads = B * N * POOL * POOL * 64;
    int blocks = (total_threads + 255) / 256;
    roi_align_kernel<<<blocks, 256, 0, stream>>>(boxes, ishape, p2, p3, p4, p5, out, B, N);
}